// Round 9
// baseline (494.999 us; speedup 1.0000x reference)
//
#include <hip/hip_runtime.h>
#include <math.h>

#define CC 64
#define KK 20
#define DCH 32
#define EM_ROWS 128
#define LOG2E 1.4426950408889634f
#define LN2   0.6931471805599453f
#define LN2PI 1.8378770664093453f
#define BIGN  -1.0e9f

#if __has_builtin(__builtin_amdgcn_exp2f)
#define EXP2(x) __builtin_amdgcn_exp2f(x)
#else
#define EXP2(x) exp2f(x)
#endif
#if __has_builtin(__builtin_amdgcn_logf)
#define LOG2(x) __builtin_amdgcn_logf(x)
#else
#define LOG2(x) log2f(x)
#endif

typedef float v2f __attribute__((ext_vector_type(2)));
typedef float v4f __attribute__((ext_vector_type(4)));

__device__ __forceinline__ v2f pk_fma(v2f a, v2f b, v2f c) {
  v2f d;
  asm("v_pk_fma_f32 %0, %1, %2, %3" : "=v"(d) : "v"(a), "v"(b), "v"(c));
  return d;
}

template <int Ctrl, int OldBits>
__device__ __forceinline__ float dpp_mov(float x) {
  return __int_as_float(__builtin_amdgcn_update_dpp(
      OldBits, __float_as_int(x), Ctrl, 0xf, 0xf, false));
}

__device__ __forceinline__ float wave_max64(float x) {
  constexpr int NI = (int)0xff800000;  // -inf
  x = fmaxf(x, dpp_mov<0x111, NI>(x));
  x = fmaxf(x, dpp_mov<0x112, NI>(x));
  x = fmaxf(x, dpp_mov<0x114, NI>(x));
  x = fmaxf(x, dpp_mov<0x118, NI>(x));
  x = fmaxf(x, dpp_mov<0x142, NI>(x));
  x = fmaxf(x, dpp_mov<0x143, NI>(x));
  return __int_as_float(__builtin_amdgcn_readlane(__float_as_int(x), 63));
}

__device__ __forceinline__ float wave_sum64(float x) {
  x += dpp_mov<0x111, 0>(x);
  x += dpp_mov<0x112, 0>(x);
  x += dpp_mov<0x114, 0>(x);
  x += dpp_mov<0x118, 0>(x);
  x += dpp_mov<0x142, 0>(x);
  x += dpp_mov<0x143, 0>(x);
  return __int_as_float(__builtin_amdgcn_readlane(__float_as_int(x), 63));
}

// ---------------------------------------------------------------------------
// Setup (unchanged)
// ---------------------------------------------------------------------------
__global__ void setup_kernel(const float* __restrict__ means,
                             const float* __restrict__ cov,
                             const float* __restrict__ tl,
                             const float* __restrict__ il,
                             const float* __restrict__ plr,
                             float* __restrict__ wmat,
                             float* __restrict__ invvar,
                             float* __restrict__ sinv,
                             float* __restrict__ q2,
                             float* __restrict__ P_T,
                             float* __restrict__ init2,
                             float* __restrict__ len2,
                             int D) {
  __shared__ float red[256];
  int tid = threadIdx.x;
  for (int d = tid; d < D; d += 256) {
    float v = 1.0f / cov[(size_t)d * D + d];
    invvar[d] = v;
    sinv[d] = sqrtf(v);
  }
  float lp_ = 0.f;
  for (int d = tid; d < D; d += 256) lp_ += logf(cov[(size_t)d * D + d]);
  red[tid] = lp_;
  __syncthreads();
  for (int s = 128; s > 0; s >>= 1) {
    if (tid < s) red[tid] += red[tid + s];
    __syncthreads();
  }
  float logdet = red[0];
  __syncthreads();
  {
    int c = tid & 63, q = tid >> 6;
    int dq = D / 4;
    float m2p = 0.f;
    for (int d = q * dq; d < (q + 1) * dq; ++d) {
      float mu = means[c * D + d];
      m2p = fmaf(mu * mu, invvar[d], m2p);
    }
    red[tid] = m2p;
  }
  __syncthreads();
  for (int i = tid; i < CC * D; i += 256) wmat[i] = means[i] * sinv[i % D];
  if (tid < CC) {
    int c = tid;
    float m2 = red[c] + red[c + 64] + red[c + 128] + red[c + 192];
    q2[c] = -0.5f * LOG2E * (m2 + logdet + (float)D * LN2PI);
    int j = c;
    float mx = -1e30f;
    for (int i2 = 0; i2 < CC; ++i2) {
      float v = (i2 == j) ? BIGN : tl[i2 * CC + j];
      mx = fmaxf(mx, v);
    }
    float s = 0.f;
    for (int i2 = 0; i2 < CC; ++i2) {
      float v = (i2 == j) ? BIGN : tl[i2 * CC + j];
      s += expf(v - mx);
    }
    float inv = 1.f / s;
    for (int i2 = 0; i2 < CC; ++i2) {
      float v = (i2 == j) ? BIGN : tl[i2 * CC + j];
      P_T[j * CC + i2] = expf(v - mx) * inv;
    }
    float mi = -1e30f;
    for (int i2 = 0; i2 < CC; ++i2) mi = fmaxf(mi, il[i2]);
    float si = 0.f;
    for (int i2 = 0; i2 < CC; ++i2) si += expf(il[i2] - mi);
    init2[c] = LOG2E * (il[c] - (mi + logf(si)));
  }
  for (int i = tid; i < KK * CC; i += 256) {
    int k = i / CC, c = i % CC;
    float lr = plr[c];
    float lp = (float)(k + 1) * lr - expf(lr) - lgammaf((float)(k + 2));
    len2[i] = LOG2E * lp;
  }
}

// ---------------------------------------------------------------------------
// Emission v3: 128-thread blocks, 128x64 tile, 8x8 register blocking.
//   4 ds_read_b128 per 64 FMA (1:16 vs old 1:8) -> total LDS-read insts halved.
//   Each thread stages exactly its OWN x-row -> x2 is thread-local (no
//   cross-lane reduce). sinv read via wave-uniform addresses -> s_load (free).
//   Register prefetch of next chunk under the inner loop.
// ---------------------------------------------------------------------------
__global__ __launch_bounds__(128, 1) void emission_kernel(
    const float* __restrict__ feat,
    const float* __restrict__ wmat,
    const float* __restrict__ sinv,
    const float* __restrict__ q2,
    float* __restrict__ emhat,
    float* __restrict__ kmax,
    int D) {
  __shared__ __align__(16) float xsT[DCH][EM_ROWS + 4];  // 32x132x4 ~16.9KB
  __shared__ __align__(16) float wsT[DCH][CC + 4];       // 32x68x4  ~8.7KB
  __shared__ float q2s[CC];
  __shared__ float x2sh[EM_ROWS];
  __shared__ float rmx[EM_ROWS][9];
  __shared__ float kapsh[EM_ROWS];

  int tid = threadIdx.x;                 // 0..127
  size_t row0 = (size_t)blockIdx.x * EM_ROWS;
  if (tid < CC) q2s[tid] = q2[tid];
  int tx = tid & 7;                      // col block: c0 = 8*tx
  int ty = tid >> 3;                     // row block: r0 = 8*ty
  int r0 = ty * 8, c0 = tx * 8;

  const float* fx = feat + (row0 + (size_t)tid) * D;  // this thread's x row
  int wc = tid >> 1;                     // w class 0..63
  int wh = (tid & 1) * 16;               // half offset 0 or 16
  const float* fw = wmat + (size_t)wc * D + wh;

  float acc[8][8] = {{0.f}};
  float x2p = 0.f;

  // prefetch chunk 0
  float4 px[8], pw[4];
  #pragma unroll
  for (int j4 = 0; j4 < 8; ++j4) px[j4] = *(const float4*)(fx + j4 * 4);
  #pragma unroll
  for (int j4 = 0; j4 < 4; ++j4) pw[j4] = *(const float4*)(fw + j4 * 4);

  for (int d0 = 0; d0 < D; d0 += DCH) {
    __syncthreads();   // previous inner-loop reads done; safe to overwrite
    // ---- stage x row (scaled) + accumulate x2; stage w half-row ----
    #pragma unroll
    for (int j4 = 0; j4 < 8; ++j4) {
      // uniform addresses -> scalar loads (SGPR broadcast, no VALU/DS cost)
      float s0 = sinv[d0 + j4 * 4 + 0];
      float s1 = sinv[d0 + j4 * 4 + 1];
      float s2 = sinv[d0 + j4 * 4 + 2];
      float s3 = sinv[d0 + j4 * 4 + 3];
      float a0 = px[j4].x * s0, a1 = px[j4].y * s1;
      float a2 = px[j4].z * s2, a3 = px[j4].w * s3;
      xsT[j4 * 4 + 0][tid] = a0;
      xsT[j4 * 4 + 1][tid] = a1;
      xsT[j4 * 4 + 2][tid] = a2;
      xsT[j4 * 4 + 3][tid] = a3;
      x2p = fmaf(a0, a0, x2p);
      x2p = fmaf(a1, a1, x2p);
      x2p = fmaf(a2, a2, x2p);
      x2p = fmaf(a3, a3, x2p);
    }
    #pragma unroll
    for (int j4 = 0; j4 < 4; ++j4) {
      wsT[wh + j4 * 4 + 0][wc] = pw[j4].x;
      wsT[wh + j4 * 4 + 1][wc] = pw[j4].y;
      wsT[wh + j4 * 4 + 2][wc] = pw[j4].z;
      wsT[wh + j4 * 4 + 3][wc] = pw[j4].w;
    }
    __syncthreads();
    // ---- prefetch next chunk (latency hides under inner loop) ----
    if (d0 + DCH < D) {
      #pragma unroll
      for (int j4 = 0; j4 < 8; ++j4)
        px[j4] = *(const float4*)(fx + d0 + DCH + j4 * 4);
      #pragma unroll
      for (int j4 = 0; j4 < 4; ++j4)
        pw[j4] = *(const float4*)(fw + d0 + DCH + j4 * 4);
    }
    // ---- inner: 4 b128 reads per 64 FMA ----
    #pragma unroll
    for (int j = 0; j < DCH; ++j) {
      float4 xa = *(const float4*)&xsT[j][r0];
      float4 xb = *(const float4*)&xsT[j][r0 + 4];
      float4 wa = *(const float4*)&wsT[j][c0];
      float4 wb = *(const float4*)&wsT[j][c0 + 4];
      float xr[8] = {xa.x, xa.y, xa.z, xa.w, xb.x, xb.y, xb.z, xb.w};
      float wr[8] = {wa.x, wa.y, wa.z, wa.w, wb.x, wb.y, wb.z, wb.w};
      #pragma unroll
      for (int r = 0; r < 8; ++r) {
        #pragma unroll
        for (int q = 0; q < 8; ++q)
          acc[r][q] = fmaf(xr[r], wr[q], acc[r][q]);
      }
    }
  }

  // ---- epilogue ----
  x2sh[tid] = x2p;
  __syncthreads();

  float e[8][8];
  #pragma unroll
  for (int r = 0; r < 8; ++r) {
    float h = 0.5f * x2sh[r0 + r];
    #pragma unroll
    for (int q = 0; q < 8; ++q)
      e[r][q] = LOG2E * (acc[r][q] - h) + q2s[c0 + q];
  }
  #pragma unroll
  for (int r = 0; r < 8; ++r) {
    float m = e[r][0];
    #pragma unroll
    for (int q = 1; q < 8; ++q) m = fmaxf(m, e[r][q]);
    rmx[r0 + r][tx] = m;
  }
  __syncthreads();
  {
    float m = rmx[tid][0];
    #pragma unroll
    for (int q = 1; q < 8; ++q) m = fmaxf(m, rmx[tid][q]);
    kapsh[tid] = m;
    kmax[row0 + tid] = m;
  }
  __syncthreads();
  #pragma unroll
  for (int r = 0; r < 8; ++r) {
    float kp = kapsh[r0 + r];
    size_t row = row0 + r0 + r;
    float4 o0, o1;
    o0.x = EXP2(e[r][0] - kp); o0.y = EXP2(e[r][1] - kp);
    o0.z = EXP2(e[r][2] - kp); o0.w = EXP2(e[r][3] - kp);
    o1.x = EXP2(e[r][4] - kp); o1.y = EXP2(e[r][5] - kp);
    o1.z = EXP2(e[r][6] - kp); o1.w = EXP2(e[r][7] - kp);
    *(float4*)&emhat[row * CC + c0] = o0;
    *(float4*)&emhat[row * CC + c0 + 4] = o1;
  }
}

// ---------------------------------------------------------------------------
// Recursion v6 (unchanged from R8: LDS-broadcast matvec + two-step fusion,
// 278us measured)
// ---------------------------------------------------------------------------
__global__ __launch_bounds__(64, 1) void recur_kernel(
    const float* __restrict__ emhat,
    const float* __restrict__ kmax,
    const float* __restrict__ P_T,
    const float* __restrict__ init2,
    const float* __restrict__ len2,
    const int* __restrict__ lengths,
    float* __restrict__ out,
    int N) {
  __shared__ __align__(16) float abuf[CC];
  int b = blockIdx.x;
  int c = threadIdx.x;

  v2f P2[CC / 2];
  #pragma unroll
  for (int j = 0; j < CC / 2; ++j) {
    v2f p;
    p.x = P_T[(size_t)(2 * j) * CC + c];
    p.y = P_T[(size_t)(2 * j + 1) * CC + c];
    P2[j] = p;
  }
  float W[KK + 1];
  #pragma unroll
  for (int k = 1; k <= KK; ++k) W[k] = EXP2(len2[(k - 1) * CC + c]);
  float W1 = W[1];

  const float* eh_b = emhat + (size_t)b * N * CC;
  const float* km_b = kmax + (size_t)b * N;
  int len_b = lengths[b];

  float skp = 0.f;
  for (int r = c; r < len_b; r += 64) skp += km_b[r];
  float Skap = wave_sum64(skp);

  float v = EXP2(init2[c]);
  float rho = eh_b[c];  // row 0
  float q0v = eh_b[(size_t)(1 <= N - 1 ? 1 : N - 1) * CC + c];
  float q1v = eh_b[(size_t)(2 <= N - 1 ? 2 : N - 1) * CC + c];
  float q2v = eh_b[(size_t)(3 <= N - 1 ? 3 : N - 1) * CC + c];
  float q3v = eh_b[(size_t)(4 <= N - 1 ? 4 : N - 1) * CC + c];
  float EfSum = 0.f;
  float A[KK];
  #pragma unroll
  for (int i = 0; i < KK; ++i) A[i] = 0.f;
  float rest = 0.f;

  auto matvec = [&](float a) -> float {
    abuf[c] = a;
    v2f a2[CC / 2];
    #pragma unroll
    for (int j = 0; j < CC / 4; ++j) {
      v4f t4 = *(v4f*)&abuf[4 * j];
      v2f lo, hi;
      lo.x = t4.x; lo.y = t4.y;
      hi.x = t4.z; hi.y = t4.w;
      a2[2 * j] = lo;
      a2[2 * j + 1] = hi;
    }
    v2f m0 = {0.f, 0.f}, m1 = {0.f, 0.f}, m2 = {0.f, 0.f}, m3 = {0.f, 0.f};
    #pragma unroll
    for (int j = 0; j < CC / 2; j += 4) {
      m0 = pk_fma(P2[j],     a2[j],     m0);
      m1 = pk_fma(P2[j + 1], a2[j + 1], m1);
      m2 = pk_fma(P2[j + 2], a2[j + 2], m2);
      m3 = pk_fma(P2[j + 3], a2[j + 3], m3);
    }
    return ((m0.x + m0.y) + (m1.x + m1.y)) + ((m2.x + m2.y) + (m3.x + m3.y));
  };

  auto body2 = [&](int t, float& qA, float& qB) {
    // ===== sub-step a (t) =====
    float A0a = v * rho;
    float aa = fmaf(A0a, W1, rest);

    abuf[c] = aa;
    v2f a2[CC / 2];
    #pragma unroll
    for (int j = 0; j < CC / 4; ++j) {
      v4f t4 = *(v4f*)&abuf[4 * j];
      v2f lo, hi;
      lo.x = t4.x; lo.y = t4.y;
      hi.x = t4.z; hi.y = t4.w;
      a2[2 * j] = lo;
      a2[2 * j + 1] = hi;
    }

    if (t == len_b) {
      float s_ = wave_sum64(aa);
      if (c == 0) out[b] = LN2 * (Skap + EfSum + LOG2(s_));
    }

    float d10 = 0.f, d11 = 0.f, d12 = 0.f, d13 = 0.f;
    #pragma unroll
    for (int i = 1; i + 3 <= 16; i += 4) {
      d10 = fmaf(A[i],     W[i + 2], d10);
      d11 = fmaf(A[i + 1], W[i + 3], d11);
      d12 = fmaf(A[i + 2], W[i + 4], d12);
      d13 = fmaf(A[i + 3], W[i + 5], d13);
    }
    d10 = fmaf(A[17], W[19], d10);
    d11 = fmaf(A[18], W[20], d11);
    float D1 = (d10 + d11) + (d12 + d13);

    float vmax = wave_max64(v);
    vmax = fminf(fmaxf(vmax, 1e-20f), 1e20f);
    int eb = (__float_as_int(vmax) >> 23) & 255;
    float scale = __int_as_float((254 - eb) << 23);
    EfSum += (float)(eb - 127);

    float rha = qA;
    int rowa = (t + 4 <= N - 1) ? (t + 4) : (N - 1);
    qA = eh_b[(size_t)rowa * CC + c];
    float rhon_a = rha * scale;

    float S2a = fmaf(A0a, W[2], D1);
    rest = rhon_a * S2a;

    {
      v2f m0 = {0.f, 0.f}, m1 = {0.f, 0.f}, m2 = {0.f, 0.f}, m3 = {0.f, 0.f};
      #pragma unroll
      for (int j = 0; j < CC / 2; j += 4) {
        m0 = pk_fma(P2[j],     a2[j],     m0);
        m1 = pk_fma(P2[j + 1], a2[j + 1], m1);
        m2 = pk_fma(P2[j + 2], a2[j + 2], m2);
        m3 = pk_fma(P2[j + 3], a2[j + 3], m3);
      }
      v = ((m0.x + m0.y) + (m1.x + m1.y)) + ((m2.x + m2.y) + (m3.x + m3.y));
    }

    // ===== sub-step b (t+1) =====
    float A0b = v * rhon_a;
    float ab = fmaf(A0b, W1, rest);

    abuf[c] = ab;
    v2f b2[CC / 2];
    #pragma unroll
    for (int j = 0; j < CC / 4; ++j) {
      v4f t4 = *(v4f*)&abuf[4 * j];
      v2f lo, hi;
      lo.x = t4.x; lo.y = t4.y;
      hi.x = t4.z; hi.y = t4.w;
      b2[2 * j] = lo;
      b2[2 * j + 1] = hi;
    }

    if (t + 1 == len_b) {
      float s_ = wave_sum64(ab);
      if (c == 0) out[b] = LN2 * (Skap + EfSum + LOG2(s_));
    }

    float d20 = 0.f, d21 = 0.f, d22 = 0.f, d23 = 0.f;
    #pragma unroll
    for (int i = 1; i + 3 <= 16; i += 4) {
      d20 = fmaf(A[i],     W[i + 3], d20);
      d21 = fmaf(A[i + 1], W[i + 4], d21);
      d22 = fmaf(A[i + 2], W[i + 5], d22);
      d23 = fmaf(A[i + 3], W[i + 6], d23);
    }
    d20 = fmaf(A[17], W[20], d20);
    float D2 = (d20 + d21) + (d22 + d23);

    float rhb = qB;
    int rowb = (t + 5 <= N - 1) ? (t + 5) : (N - 1);
    qB = eh_b[(size_t)rowb * CC + c];
    float rhon_b = rhb;  // no renorm this sub-step

    float S2b = fmaf(A0b, W[2], rhon_a * fmaf(A0a, W[3], D2));
    rest = rhon_b * S2b;

    float r2 = rhon_a * rhon_b;
    #pragma unroll
    for (int i = 18; i >= 3; --i) A[i] = A[i - 2] * r2;
    A[2] = A0a * r2;
    A[1] = A0b * rhon_b;

    {
      v2f m0 = {0.f, 0.f}, m1 = {0.f, 0.f}, m2 = {0.f, 0.f}, m3 = {0.f, 0.f};
      #pragma unroll
      for (int j = 0; j < CC / 2; j += 4) {
        m0 = pk_fma(P2[j],     b2[j],     m0);
        m1 = pk_fma(P2[j + 1], b2[j + 1], m1);
        m2 = pk_fma(P2[j + 2], b2[j + 2], m2);
        m3 = pk_fma(P2[j + 3], b2[j + 3], m3);
      }
      v = ((m0.x + m0.y) + (m1.x + m1.y)) + ((m2.x + m2.y) + (m3.x + m3.y));
    }

    rho = rhon_b;
  };

  auto body1 = [&](int t, float& q) {
    float A0 = v * rho;
    float a = fmaf(A0, W1, rest);
    float vn = matvec(a);
    if (t == len_b) {
      float s_ = wave_sum64(a);
      if (c == 0) out[b] = LN2 * (Skap + EfSum + LOG2(s_));
    }
    float d10 = A0 * W[2], d11 = 0.f, d12 = 0.f, d13 = 0.f;
    #pragma unroll
    for (int i = 1; i + 3 <= 16; i += 4) {
      d10 = fmaf(A[i],     W[i + 2], d10);
      d11 = fmaf(A[i + 1], W[i + 3], d11);
      d12 = fmaf(A[i + 2], W[i + 4], d12);
      d13 = fmaf(A[i + 3], W[i + 5], d13);
    }
    d11 = fmaf(A[17], W[19], d11);
    d12 = fmaf(A[18], W[20], d12);
    float S2 = (d10 + d11) + (d12 + d13);
    float rh = q;
    int rown = (t + 4 <= N - 1) ? (t + 4) : (N - 1);
    q = eh_b[(size_t)rown * CC + c];
    float vmax = wave_max64(v);
    vmax = fminf(fmaxf(vmax, 1e-20f), 1e20f);
    int eb = (__float_as_int(vmax) >> 23) & 255;
    float scale = __int_as_float((254 - eb) << 23);
    EfSum += (float)(eb - 127);
    float rhon = rh * scale;
    rest = rhon * S2;
    #pragma unroll
    for (int i = 18; i >= 2; --i) A[i] = A[i - 1] * rhon;
    A[1] = A0 * rhon;
    v = vn;
    rho = rhon;
  };

  int t = 1;
  for (; t + 3 <= N; t += 4) {
    body2(t,     q0v, q1v);
    body2(t + 2, q2v, q3v);
  }
  for (; t <= N; ++t) {
    int s = t & 3;
    if (s == 1)      body1(t, q0v);
    else if (s == 2) body1(t, q1v);
    else if (s == 3) body1(t, q2v);
    else             body1(t, q3v);
  }
}

extern "C" void kernel_launch(void* const* d_in, const int* in_sizes, int n_in,
                              void* d_out, int out_size, void* d_ws, size_t ws_size,
                              hipStream_t stream) {
  const float* feat   = (const float*)d_in[0];
  const int*   lens   = (const int*)d_in[1];
  const float* means  = (const float*)d_in[2];
  const float* cov    = (const float*)d_in[3];
  const float* tl     = (const float*)d_in[4];
  const float* il     = (const float*)d_in[5];
  const float* plr    = (const float*)d_in[6];
  int B = in_sizes[1];
  int D = in_sizes[2] / CC;
  int N = in_sizes[0] / (B * D);

  float* ws = (float*)d_ws;
  size_t off = 0;
  float* wmat   = ws + off; off += (size_t)CC * D;
  float* invvar = ws + off; off += D;
  float* sinv   = ws + off; off += D;
  float* q2     = ws + off; off += CC;
  float* P_T    = ws + off; off += CC * CC;
  float* init2  = ws + off; off += CC;
  float* len2   = ws + off; off += KK * CC;
  float* emhat  = ws + off; off += (size_t)B * N * CC;
  float* kmax   = ws + off; off += (size_t)B * N;

  hipLaunchKernelGGL(setup_kernel, dim3(1), dim3(256), 0, stream,
                     means, cov, tl, il, plr, wmat, invvar, sinv, q2, P_T, init2, len2, D);
  hipLaunchKernelGGL(emission_kernel, dim3((B * N) / EM_ROWS), dim3(128), 0, stream,
                     feat, wmat, sinv, q2, emhat, kmax, D);
  hipLaunchKernelGGL(recur_kernel, dim3(B), dim3(64), 0, stream,
                     emhat, kmax, P_T, init2, len2, lens, (float*)d_out, N);
}

// Round 10
// 447.397 us; speedup vs baseline: 1.1064x; 1.1064x over previous
//
#include <hip/hip_runtime.h>
#include <math.h>

#define CC 64
#define KK 20
#define DCH 32
#define LOG2E 1.4426950408889634f
#define LN2   0.6931471805599453f
#define LN2PI 1.8378770664093453f
#define BIGN  -1.0e9f

#if __has_builtin(__builtin_amdgcn_exp2f)
#define EXP2(x) __builtin_amdgcn_exp2f(x)
#else
#define EXP2(x) exp2f(x)
#endif
#if __has_builtin(__builtin_amdgcn_logf)
#define LOG2(x) __builtin_amdgcn_logf(x)
#else
#define LOG2(x) log2f(x)
#endif

typedef float v2f __attribute__((ext_vector_type(2)));
typedef float v4f __attribute__((ext_vector_type(4)));

__device__ __forceinline__ v2f pk_fma(v2f a, v2f b, v2f c) {
  v2f d;
  asm("v_pk_fma_f32 %0, %1, %2, %3" : "=v"(d) : "v"(a), "v"(b), "v"(c));
  return d;
}

template <int Ctrl, int OldBits>
__device__ __forceinline__ float dpp_mov(float x) {
  return __int_as_float(__builtin_amdgcn_update_dpp(
      OldBits, __float_as_int(x), Ctrl, 0xf, 0xf, false));
}

__device__ __forceinline__ float wave_max64(float x) {
  constexpr int NI = (int)0xff800000;  // -inf
  x = fmaxf(x, dpp_mov<0x111, NI>(x));
  x = fmaxf(x, dpp_mov<0x112, NI>(x));
  x = fmaxf(x, dpp_mov<0x114, NI>(x));
  x = fmaxf(x, dpp_mov<0x118, NI>(x));
  x = fmaxf(x, dpp_mov<0x142, NI>(x));
  x = fmaxf(x, dpp_mov<0x143, NI>(x));
  return __int_as_float(__builtin_amdgcn_readlane(__float_as_int(x), 63));
}

__device__ __forceinline__ float wave_sum64(float x) {
  x += dpp_mov<0x111, 0>(x);
  x += dpp_mov<0x112, 0>(x);
  x += dpp_mov<0x114, 0>(x);
  x += dpp_mov<0x118, 0>(x);
  x += dpp_mov<0x142, 0>(x);
  x += dpp_mov<0x143, 0>(x);
  return __int_as_float(__builtin_amdgcn_readlane(__float_as_int(x), 63));
}

// ---------------------------------------------------------------------------
// Setup (unchanged)
// ---------------------------------------------------------------------------
__global__ void setup_kernel(const float* __restrict__ means,
                             const float* __restrict__ cov,
                             const float* __restrict__ tl,
                             const float* __restrict__ il,
                             const float* __restrict__ plr,
                             float* __restrict__ wmat,
                             float* __restrict__ invvar,
                             float* __restrict__ sinv,
                             float* __restrict__ q2,
                             float* __restrict__ P_T,
                             float* __restrict__ init2,
                             float* __restrict__ len2,
                             int D) {
  __shared__ float red[256];
  int tid = threadIdx.x;
  for (int d = tid; d < D; d += 256) {
    float v = 1.0f / cov[(size_t)d * D + d];
    invvar[d] = v;
    sinv[d] = sqrtf(v);
  }
  float lp_ = 0.f;
  for (int d = tid; d < D; d += 256) lp_ += logf(cov[(size_t)d * D + d]);
  red[tid] = lp_;
  __syncthreads();
  for (int s = 128; s > 0; s >>= 1) {
    if (tid < s) red[tid] += red[tid + s];
    __syncthreads();
  }
  float logdet = red[0];
  __syncthreads();
  {
    int c = tid & 63, q = tid >> 6;
    int dq = D / 4;
    float m2p = 0.f;
    for (int d = q * dq; d < (q + 1) * dq; ++d) {
      float mu = means[c * D + d];
      m2p = fmaf(mu * mu, invvar[d], m2p);
    }
    red[tid] = m2p;
  }
  __syncthreads();
  for (int i = tid; i < CC * D; i += 256) wmat[i] = means[i] * sinv[i % D];
  if (tid < CC) {
    int c = tid;
    float m2 = red[c] + red[c + 64] + red[c + 128] + red[c + 192];
    q2[c] = -0.5f * LOG2E * (m2 + logdet + (float)D * LN2PI);
    int j = c;
    float mx = -1e30f;
    for (int i2 = 0; i2 < CC; ++i2) {
      float v = (i2 == j) ? BIGN : tl[i2 * CC + j];
      mx = fmaxf(mx, v);
    }
    float s = 0.f;
    for (int i2 = 0; i2 < CC; ++i2) {
      float v = (i2 == j) ? BIGN : tl[i2 * CC + j];
      s += expf(v - mx);
    }
    float inv = 1.f / s;
    for (int i2 = 0; i2 < CC; ++i2) {
      float v = (i2 == j) ? BIGN : tl[i2 * CC + j];
      P_T[j * CC + i2] = expf(v - mx) * inv;
    }
    float mi = -1e30f;
    for (int i2 = 0; i2 < CC; ++i2) mi = fmaxf(mi, il[i2]);
    float si = 0.f;
    for (int i2 = 0; i2 < CC; ++i2) si += expf(il[i2] - mi);
    init2[c] = LOG2E * (il[c] - (mi + logf(si)));
  }
  for (int i = tid; i < KK * CC; i += 256) {
    int k = i / CC, c = i % CC;
    float lr = plr[c];
    float lp = (float)(k + 1) * lr - expf(lr) - lgammaf((float)(k + 2));
    len2[i] = LOG2E * lp;
  }
}

// ---------------------------------------------------------------------------
// Emission v4: proven v2 shape (64 rows x 64 cols, 256 threads, 4x4/thread)
// + DOUBLE-BUFFERED LDS: one __syncthreads per chunk (was 2). Order per
// chunk: barrier -> issue next-chunk global loads -> compute buf[cur] ->
// stage buf[cur^1]. Staging overlaps compute; global latency hides under
// the 32-j inner loop.
// ---------------------------------------------------------------------------
__global__ __launch_bounds__(256) void emission_kernel(
    const float* __restrict__ feat,
    const float* __restrict__ wmat,
    const float* __restrict__ sinv,
    const float* __restrict__ q2,
    float* __restrict__ emhat,
    float* __restrict__ kmax,
    int D) {
  __shared__ __align__(16) float xsT[2][DCH][68];
  __shared__ __align__(16) float wsT[2][DCH][68];
  __shared__ float q2s[CC];
  __shared__ float x2row[64];
  __shared__ float rmx[64][17];
  __shared__ float kapsh[64];
  int tid = threadIdx.x;
  size_t row0 = (size_t)blockIdx.x * 64;
  if (tid < CC) q2s[tid] = q2[tid];
  int lr_ = tid >> 2;
  int lq  = tid & 3;
  int lj  = lq * 8;
  int tx = tid & 15, ty = tid >> 4;
  int r0 = ty * 4, c0 = tx * 4;

  const float* fx = feat + (row0 + (size_t)lr_) * D + lj;
  const float* fw = wmat + (size_t)lr_ * D + lj;
  const float* fs = sinv + lj;

  float4 xa = *(const float4*)(fx);
  float4 xb = *(const float4*)(fx + 4);
  float4 wa = *(const float4*)(fw);
  float4 wb = *(const float4*)(fw + 4);
  float4 sa = *(const float4*)(fs);
  float4 sb = *(const float4*)(fs + 4);

  float acc[4][4] = {{0.f}};
  float x2p = 0.f;

  // stage chunk 0 -> buf 0
  {
    float xs0 = xa.x * sa.x, xs1 = xa.y * sa.y, xs2 = xa.z * sa.z, xs3 = xa.w * sa.w;
    float xs4 = xb.x * sb.x, xs5 = xb.y * sb.y, xs6 = xb.z * sb.z, xs7 = xb.w * sb.w;
    xsT[0][lj + 0][lr_] = xs0; xsT[0][lj + 1][lr_] = xs1;
    xsT[0][lj + 2][lr_] = xs2; xsT[0][lj + 3][lr_] = xs3;
    xsT[0][lj + 4][lr_] = xs4; xsT[0][lj + 5][lr_] = xs5;
    xsT[0][lj + 6][lr_] = xs6; xsT[0][lj + 7][lr_] = xs7;
    wsT[0][lj + 0][lr_] = wa.x; wsT[0][lj + 1][lr_] = wa.y;
    wsT[0][lj + 2][lr_] = wa.z; wsT[0][lj + 3][lr_] = wa.w;
    wsT[0][lj + 4][lr_] = wb.x; wsT[0][lj + 5][lr_] = wb.y;
    wsT[0][lj + 6][lr_] = wb.z; wsT[0][lj + 7][lr_] = wb.w;
    x2p = fmaf(xs0, xs0, x2p); x2p = fmaf(xs1, xs1, x2p);
    x2p = fmaf(xs2, xs2, x2p); x2p = fmaf(xs3, xs3, x2p);
    x2p = fmaf(xs4, xs4, x2p); x2p = fmaf(xs5, xs5, x2p);
    x2p = fmaf(xs6, xs6, x2p); x2p = fmaf(xs7, xs7, x2p);
  }
  int cur = 0;
  for (int d0 = 0; d0 < D; d0 += DCH) {
    __syncthreads();   // buf[cur] staged by all; buf[cur^1] dead
    bool more = (d0 + DCH) < D;
    if (more) {
      xa = *(const float4*)(fx + d0 + DCH);
      xb = *(const float4*)(fx + d0 + DCH + 4);
      wa = *(const float4*)(fw + d0 + DCH);
      wb = *(const float4*)(fw + d0 + DCH + 4);
      sa = *(const float4*)(fs + d0 + DCH);
      sb = *(const float4*)(fs + d0 + DCH + 4);
    }
    #pragma unroll
    for (int j = 0; j < DCH; ++j) {
      float4 xv = *(const float4*)&xsT[cur][j][r0];
      float4 wv = *(const float4*)&wsT[cur][j][c0];
      acc[0][0] = fmaf(xv.x, wv.x, acc[0][0]);
      acc[0][1] = fmaf(xv.x, wv.y, acc[0][1]);
      acc[0][2] = fmaf(xv.x, wv.z, acc[0][2]);
      acc[0][3] = fmaf(xv.x, wv.w, acc[0][3]);
      acc[1][0] = fmaf(xv.y, wv.x, acc[1][0]);
      acc[1][1] = fmaf(xv.y, wv.y, acc[1][1]);
      acc[1][2] = fmaf(xv.y, wv.z, acc[1][2]);
      acc[1][3] = fmaf(xv.y, wv.w, acc[1][3]);
      acc[2][0] = fmaf(xv.z, wv.x, acc[2][0]);
      acc[2][1] = fmaf(xv.z, wv.y, acc[2][1]);
      acc[2][2] = fmaf(xv.z, wv.z, acc[2][2]);
      acc[2][3] = fmaf(xv.z, wv.w, acc[2][3]);
      acc[3][0] = fmaf(xv.w, wv.x, acc[3][0]);
      acc[3][1] = fmaf(xv.w, wv.y, acc[3][1]);
      acc[3][2] = fmaf(xv.w, wv.z, acc[3][2]);
      acc[3][3] = fmaf(xv.w, wv.w, acc[3][3]);
    }
    if (more) {
      int nxt = cur ^ 1;
      float xs0 = xa.x * sa.x, xs1 = xa.y * sa.y, xs2 = xa.z * sa.z, xs3 = xa.w * sa.w;
      float xs4 = xb.x * sb.x, xs5 = xb.y * sb.y, xs6 = xb.z * sb.z, xs7 = xb.w * sb.w;
      xsT[nxt][lj + 0][lr_] = xs0; xsT[nxt][lj + 1][lr_] = xs1;
      xsT[nxt][lj + 2][lr_] = xs2; xsT[nxt][lj + 3][lr_] = xs3;
      xsT[nxt][lj + 4][lr_] = xs4; xsT[nxt][lj + 5][lr_] = xs5;
      xsT[nxt][lj + 6][lr_] = xs6; xsT[nxt][lj + 7][lr_] = xs7;
      wsT[nxt][lj + 0][lr_] = wa.x; wsT[nxt][lj + 1][lr_] = wa.y;
      wsT[nxt][lj + 2][lr_] = wa.z; wsT[nxt][lj + 3][lr_] = wa.w;
      wsT[nxt][lj + 4][lr_] = wb.x; wsT[nxt][lj + 5][lr_] = wb.y;
      wsT[nxt][lj + 6][lr_] = wb.z; wsT[nxt][lj + 7][lr_] = wb.w;
      x2p = fmaf(xs0, xs0, x2p); x2p = fmaf(xs1, xs1, x2p);
      x2p = fmaf(xs2, xs2, x2p); x2p = fmaf(xs3, xs3, x2p);
      x2p = fmaf(xs4, xs4, x2p); x2p = fmaf(xs5, xs5, x2p);
      x2p = fmaf(xs6, xs6, x2p); x2p = fmaf(xs7, xs7, x2p);
    }
    cur ^= 1;
  }

  x2p += dpp_mov<0xB1, 0>(x2p);
  x2p += dpp_mov<0x4E, 0>(x2p);
  if (lq == 0) x2row[lr_] = x2p;
  __syncthreads();

  float e[4][4];
  #pragma unroll
  for (int i = 0; i < 4; ++i) {
    float h = 0.5f * x2row[r0 + i];
    #pragma unroll
    for (int k2 = 0; k2 < 4; ++k2)
      e[i][k2] = LOG2E * (acc[i][k2] - h) + q2s[c0 + k2];
  }
  #pragma unroll
  for (int i = 0; i < 4; ++i)
    rmx[r0 + i][tx] = fmaxf(fmaxf(e[i][0], e[i][1]), fmaxf(e[i][2], e[i][3]));
  __syncthreads();
  if (tid < 64) {
    float m = rmx[tid][0];
    #pragma unroll
    for (int j = 1; j < 16; ++j) m = fmaxf(m, rmx[tid][j]);
    kapsh[tid] = m;
    kmax[row0 + tid] = m;
  }
  __syncthreads();
  #pragma unroll
  for (int i = 0; i < 4; ++i) {
    float kp = kapsh[r0 + i];
    size_t row = row0 + r0 + i;
    float4 o;
    o.x = EXP2(e[i][0] - kp); o.y = EXP2(e[i][1] - kp);
    o.z = EXP2(e[i][2] - kp); o.w = EXP2(e[i][3] - kp);
    *(float4*)&emhat[row * CC + c0] = o;
  }
}

// ---------------------------------------------------------------------------
// Recursion v7: LDS-broadcast matvec (R7) + QUAD fusion (extends verified
// R8 pair fusion). Per quad (t..t+3):
//   D1..D4 = shifted dots over OLD ring (66 fma, one shared loop)
//   S2_a = A0a W2 + D1
//   S2_b = A0b W2 + ra(A0a W3 + D2)
//   S2_c = A0c W2 + rb(A0b W3 + ra(A0a W4 + D3))
//   S2_d = A0d W2 + rc(A0c W3 + rb(A0b W4 + ra(A0a W5 + D4)))
//   ring shifts ONCE by 4; renorm ONCE per quad (scale folded into ra).
// ---------------------------------------------------------------------------
__global__ __launch_bounds__(64, 1) void recur_kernel(
    const float* __restrict__ emhat,
    const float* __restrict__ kmax,
    const float* __restrict__ P_T,
    const float* __restrict__ init2,
    const float* __restrict__ len2,
    const int* __restrict__ lengths,
    float* __restrict__ out,
    int N) {
  __shared__ __align__(16) float abuf[CC];
  int b = blockIdx.x;
  int c = threadIdx.x;

  v2f P2[CC / 2];
  #pragma unroll
  for (int j = 0; j < CC / 2; ++j) {
    v2f p;
    p.x = P_T[(size_t)(2 * j) * CC + c];
    p.y = P_T[(size_t)(2 * j + 1) * CC + c];
    P2[j] = p;
  }
  float W[KK + 1];
  #pragma unroll
  for (int k = 1; k <= KK; ++k) W[k] = EXP2(len2[(k - 1) * CC + c]);
  float W1 = W[1];

  const float* eh_b = emhat + (size_t)b * N * CC;
  const float* km_b = kmax + (size_t)b * N;
  int len_b = lengths[b];

  float skp = 0.f;
  for (int r = c; r < len_b; r += 64) skp += km_b[r];
  float Skap = wave_sum64(skp);

  float v = EXP2(init2[c]);
  float rho = eh_b[c];  // row 0
  float qa = eh_b[(size_t)(1 <= N - 1 ? 1 : N - 1) * CC + c];
  float qb = eh_b[(size_t)(2 <= N - 1 ? 2 : N - 1) * CC + c];
  float qc = eh_b[(size_t)(3 <= N - 1 ? 3 : N - 1) * CC + c];
  float qd = eh_b[(size_t)(4 <= N - 1 ? 4 : N - 1) * CC + c];
  float EfSum = 0.f;
  float A[KK];
  #pragma unroll
  for (int i = 0; i < KK; ++i) A[i] = 0.f;
  float rest = 0.f;

  // LDS broadcast + packed matvec: issues write+reads; consumes with pk_fma
  auto bcast = [&](float a, v2f* dst) {
    abuf[c] = a;
    #pragma unroll
    for (int j = 0; j < CC / 4; ++j) {
      v4f t4 = *(v4f*)&abuf[4 * j];
      v2f lo, hi;
      lo.x = t4.x; lo.y = t4.y;
      hi.x = t4.z; hi.y = t4.w;
      dst[2 * j] = lo;
      dst[2 * j + 1] = hi;
    }
  };
  auto consume = [&](const v2f* a2) -> float {
    v2f m0 = {0.f, 0.f}, m1 = {0.f, 0.f}, m2 = {0.f, 0.f}, m3 = {0.f, 0.f};
    #pragma unroll
    for (int j = 0; j < CC / 2; j += 4) {
      m0 = pk_fma(P2[j],     a2[j],     m0);
      m1 = pk_fma(P2[j + 1], a2[j + 1], m1);
      m2 = pk_fma(P2[j + 2], a2[j + 2], m2);
      m3 = pk_fma(P2[j + 3], a2[j + 3], m3);
    }
    return ((m0.x + m0.y) + (m1.x + m1.y)) + ((m2.x + m2.y) + (m3.x + m3.y));
  };

  auto body4 = [&](int t, float& qa_, float& qb_, float& qc_, float& qd_) {
    v2f a2[CC / 2];
    // ===== sub a (t): renorm step =====
    float A0a = v * rho;
    float aa = fmaf(A0a, W1, rest);
    bcast(aa, a2);
    if (t == len_b) {
      float s_ = wave_sum64(aa);
      if (c == 0) out[b] = LN2 * (Skap + EfSum + LOG2(s_));
    }
    // D1..D4 over OLD ring (fills DS shadow)
    float D1 = 0.f, D2 = 0.f, D3 = 0.f, D4 = 0.f;
    #pragma unroll
    for (int i = 1; i <= 15; ++i) {
      float ai = A[i];
      D1 = fmaf(ai, W[i + 2], D1);
      D2 = fmaf(ai, W[i + 3], D2);
      D3 = fmaf(ai, W[i + 4], D3);
      D4 = fmaf(ai, W[i + 5], D4);
    }
    D1 = fmaf(A[16], W[18], D1); D2 = fmaf(A[16], W[19], D2); D3 = fmaf(A[16], W[20], D3);
    D1 = fmaf(A[17], W[19], D1); D2 = fmaf(A[17], W[20], D2);
    D1 = fmaf(A[18], W[20], D1);
    // renorm (once per quad)
    float vmax = wave_max64(v);
    vmax = fminf(fmaxf(vmax, 1e-20f), 1e20f);
    int eb = (__float_as_int(vmax) >> 23) & 255;
    float scale = __int_as_float((254 - eb) << 23);
    EfSum += (float)(eb - 127);
    float ra = qa_ * scale;
    {
      int rr = (t + 4 <= N - 1) ? (t + 4) : (N - 1);
      qa_ = eh_b[(size_t)rr * CC + c];
    }
    rest = ra * fmaf(A0a, W[2], D1);
    v = consume(a2);

    // ===== sub b (t+1) =====
    float A0b = v * ra;
    float ab = fmaf(A0b, W1, rest);
    bcast(ab, a2);
    if (t + 1 == len_b) {
      float s_ = wave_sum64(ab);
      if (c == 0) out[b] = LN2 * (Skap + EfSum + LOG2(s_));
    }
    float rb = qb_;
    {
      int rr = (t + 5 <= N - 1) ? (t + 5) : (N - 1);
      qb_ = eh_b[(size_t)rr * CC + c];
    }
    rest = rb * fmaf(A0b, W[2], ra * fmaf(A0a, W[3], D2));
    v = consume(a2);

    // ===== sub c (t+2) =====
    float A0c = v * rb;
    float ac = fmaf(A0c, W1, rest);
    bcast(ac, a2);
    if (t + 2 == len_b) {
      float s_ = wave_sum64(ac);
      if (c == 0) out[b] = LN2 * (Skap + EfSum + LOG2(s_));
    }
    float rc = qc_;
    {
      int rr = (t + 6 <= N - 1) ? (t + 6) : (N - 1);
      qc_ = eh_b[(size_t)rr * CC + c];
    }
    rest = rc * fmaf(A0c, W[2], rb * fmaf(A0b, W[3], ra * fmaf(A0a, W[4], D3)));
    v = consume(a2);

    // ===== sub d (t+3) =====
    float A0d = v * rc;
    float ad = fmaf(A0d, W1, rest);
    bcast(ad, a2);
    if (t + 3 == len_b) {
      float s_ = wave_sum64(ad);
      if (c == 0) out[b] = LN2 * (Skap + EfSum + LOG2(s_));
    }
    float rd = qd_;
    {
      int rr = (t + 7 <= N - 1) ? (t + 7) : (N - 1);
      qd_ = eh_b[(size_t)rr * CC + c];
    }
    rest = rd * fmaf(A0d, W[2],
                rc * fmaf(A0c, W[3],
                rb * fmaf(A0b, W[4],
                ra * fmaf(A0a, W[5], D4))));
    // ring shift by 4 (fills DS shadow of d's broadcast)
    float rcd = rc * rd;
    float rbcd = rb * rcd;
    float r4 = ra * rbcd;
    #pragma unroll
    for (int i = 18; i >= 5; --i) A[i] = A[i - 4] * r4;
    A[4] = A0a * r4;
    A[3] = A0b * rbcd;
    A[2] = A0c * rcd;
    A[1] = A0d * rd;
    v = consume(a2);

    rho = rd;
  };

  // single-step fallback (tail; per-step renorm — exact)
  auto body1 = [&](int t, float& q) {
    v2f a2[CC / 2];
    float A0 = v * rho;
    float a = fmaf(A0, W1, rest);
    bcast(a, a2);
    if (t == len_b) {
      float s_ = wave_sum64(a);
      if (c == 0) out[b] = LN2 * (Skap + EfSum + LOG2(s_));
    }
    float d10 = A0 * W[2], d11 = 0.f, d12 = 0.f, d13 = 0.f;
    #pragma unroll
    for (int i = 1; i + 3 <= 16; i += 4) {
      d10 = fmaf(A[i],     W[i + 2], d10);
      d11 = fmaf(A[i + 1], W[i + 3], d11);
      d12 = fmaf(A[i + 2], W[i + 4], d12);
      d13 = fmaf(A[i + 3], W[i + 5], d13);
    }
    d11 = fmaf(A[17], W[19], d11);
    d12 = fmaf(A[18], W[20], d12);
    float S2 = (d10 + d11) + (d12 + d13);
    float rh = q;
    int rown = (t + 4 <= N - 1) ? (t + 4) : (N - 1);
    q = eh_b[(size_t)rown * CC + c];
    float vmax = wave_max64(v);
    vmax = fminf(fmaxf(vmax, 1e-20f), 1e20f);
    int eb = (__float_as_int(vmax) >> 23) & 255;
    float scale = __int_as_float((254 - eb) << 23);
    EfSum += (float)(eb - 127);
    float rhon = rh * scale;
    rest = rhon * S2;
    #pragma unroll
    for (int i = 18; i >= 2; --i) A[i] = A[i - 1] * rhon;
    A[1] = A0 * rhon;
    v = consume(a2);
    rho = rhon;
  };

  int t = 1;
  for (; t + 3 <= N; t += 4) body4(t, qa, qb, qc, qd);
  for (; t <= N; ++t) {
    int s = t & 3;
    if (s == 1)      body1(t, qa);
    else if (s == 2) body1(t, qb);
    else if (s == 3) body1(t, qc);
    else             body1(t, qd);
  }
}

extern "C" void kernel_launch(void* const* d_in, const int* in_sizes, int n_in,
                              void* d_out, int out_size, void* d_ws, size_t ws_size,
                              hipStream_t stream) {
  const float* feat   = (const float*)d_in[0];
  const int*   lens   = (const int*)d_in[1];
  const float* means  = (const float*)d_in[2];
  const float* cov    = (const float*)d_in[3];
  const float* tl     = (const float*)d_in[4];
  const float* il     = (const float*)d_in[5];
  const float* plr    = (const float*)d_in[6];
  int B = in_sizes[1];
  int D = in_sizes[2] / CC;
  int N = in_sizes[0] / (B * D);

  float* ws = (float*)d_ws;
  size_t off = 0;
  float* wmat   = ws + off; off += (size_t)CC * D;
  float* invvar = ws + off; off += D;
  float* sinv   = ws + off; off += D;
  float* q2     = ws + off; off += CC;
  float* P_T    = ws + off; off += CC * CC;
  float* init2  = ws + off; off += CC;
  float* len2   = ws + off; off += KK * CC;
  float* emhat  = ws + off; off += (size_t)B * N * CC;
  float* kmax   = ws + off; off += (size_t)B * N;

  hipLaunchKernelGGL(setup_kernel, dim3(1), dim3(256), 0, stream,
                     means, cov, tl, il, plr, wmat, invvar, sinv, q2, P_T, init2, len2, D);
  hipLaunchKernelGGL(emission_kernel, dim3((B * N) / 64), dim3(256), 0, stream,
                     feat, wmat, sinv, q2, emhat, kmax, D);
  hipLaunchKernelGGL(recur_kernel, dim3(B), dim3(64), 0, stream,
                     emhat, kmax, P_T, init2, len2, lens, (float*)d_out, N);
}

// Round 11
// 420.670 us; speedup vs baseline: 1.1767x; 1.0635x over previous
//
#include <hip/hip_runtime.h>
#include <math.h>

#define CC 64
#define KK 20
#define DCH 32
#define LOG2E 1.4426950408889634f
#define LN2   0.6931471805599453f
#define LN2PI 1.8378770664093453f
#define BIGN  -1.0e9f

#if __has_builtin(__builtin_amdgcn_exp2f)
#define EXP2(x) __builtin_amdgcn_exp2f(x)
#else
#define EXP2(x) exp2f(x)
#endif
#if __has_builtin(__builtin_amdgcn_logf)
#define LOG2(x) __builtin_amdgcn_logf(x)
#else
#define LOG2(x) log2f(x)
#endif

typedef float v2f __attribute__((ext_vector_type(2)));
typedef float v4f __attribute__((ext_vector_type(4)));

__device__ __forceinline__ v2f pk_fma(v2f a, v2f b, v2f c) {
  v2f d;
  asm("v_pk_fma_f32 %0, %1, %2, %3" : "=v"(d) : "v"(a), "v"(b), "v"(c));
  return d;
}

template <int Ctrl, int OldBits>
__device__ __forceinline__ float dpp_mov(float x) {
  return __int_as_float(__builtin_amdgcn_update_dpp(
      OldBits, __float_as_int(x), Ctrl, 0xf, 0xf, false));
}

__device__ __forceinline__ float wave_max64(float x) {
  constexpr int NI = (int)0xff800000;  // -inf
  x = fmaxf(x, dpp_mov<0x111, NI>(x));
  x = fmaxf(x, dpp_mov<0x112, NI>(x));
  x = fmaxf(x, dpp_mov<0x114, NI>(x));
  x = fmaxf(x, dpp_mov<0x118, NI>(x));
  x = fmaxf(x, dpp_mov<0x142, NI>(x));
  x = fmaxf(x, dpp_mov<0x143, NI>(x));
  return __int_as_float(__builtin_amdgcn_readlane(__float_as_int(x), 63));
}

__device__ __forceinline__ float wave_sum64(float x) {
  x += dpp_mov<0x111, 0>(x);
  x += dpp_mov<0x112, 0>(x);
  x += dpp_mov<0x114, 0>(x);
  x += dpp_mov<0x118, 0>(x);
  x += dpp_mov<0x142, 0>(x);
  x += dpp_mov<0x143, 0>(x);
  return __int_as_float(__builtin_amdgcn_readlane(__float_as_int(x), 63));
}

// ---------------------------------------------------------------------------
// Setup (unchanged)
// ---------------------------------------------------------------------------
__global__ void setup_kernel(const float* __restrict__ means,
                             const float* __restrict__ cov,
                             const float* __restrict__ tl,
                             const float* __restrict__ il,
                             const float* __restrict__ plr,
                             float* __restrict__ wmat,
                             float* __restrict__ invvar,
                             float* __restrict__ sinv,
                             float* __restrict__ q2,
                             float* __restrict__ P_T,
                             float* __restrict__ init2,
                             float* __restrict__ len2,
                             int D) {
  __shared__ float red[256];
  int tid = threadIdx.x;
  for (int d = tid; d < D; d += 256) {
    float v = 1.0f / cov[(size_t)d * D + d];
    invvar[d] = v;
    sinv[d] = sqrtf(v);
  }
  float lp_ = 0.f;
  for (int d = tid; d < D; d += 256) lp_ += logf(cov[(size_t)d * D + d]);
  red[tid] = lp_;
  __syncthreads();
  for (int s = 128; s > 0; s >>= 1) {
    if (tid < s) red[tid] += red[tid + s];
    __syncthreads();
  }
  float logdet = red[0];
  __syncthreads();
  {
    int c = tid & 63, q = tid >> 6;
    int dq = D / 4;
    float m2p = 0.f;
    for (int d = q * dq; d < (q + 1) * dq; ++d) {
      float mu = means[c * D + d];
      m2p = fmaf(mu * mu, invvar[d], m2p);
    }
    red[tid] = m2p;
  }
  __syncthreads();
  for (int i = tid; i < CC * D; i += 256) wmat[i] = means[i] * sinv[i % D];
  if (tid < CC) {
    int c = tid;
    float m2 = red[c] + red[c + 64] + red[c + 128] + red[c + 192];
    q2[c] = -0.5f * LOG2E * (m2 + logdet + (float)D * LN2PI);
    int j = c;
    float mx = -1e30f;
    for (int i2 = 0; i2 < CC; ++i2) {
      float v = (i2 == j) ? BIGN : tl[i2 * CC + j];
      mx = fmaxf(mx, v);
    }
    float s = 0.f;
    for (int i2 = 0; i2 < CC; ++i2) {
      float v = (i2 == j) ? BIGN : tl[i2 * CC + j];
      s += expf(v - mx);
    }
    float inv = 1.f / s;
    for (int i2 = 0; i2 < CC; ++i2) {
      float v = (i2 == j) ? BIGN : tl[i2 * CC + j];
      P_T[j * CC + i2] = expf(v - mx) * inv;
    }
    float mi = -1e30f;
    for (int i2 = 0; i2 < CC; ++i2) mi = fmaxf(mi, il[i2]);
    float si = 0.f;
    for (int i2 = 0; i2 < CC; ++i2) si += expf(il[i2] - mi);
    init2[c] = LOG2E * (il[c] - (mi + logf(si)));
  }
  for (int i = tid; i < KK * CC; i += 256) {
    int k = i / CC, c = i % CC;
    float lr = plr[c];
    float lp = (float)(k + 1) * lr - expf(lr) - lgammaf((float)(k + 2));
    len2[i] = LOG2E * lp;
  }
}

// ---------------------------------------------------------------------------
// Emission: exact R8 v2 (proven best: 64x64 tile, 256 thr, 4x4/thread,
// single-buffered transposed LDS, reg prefetch). Dbuf (R10) regressed.
// ---------------------------------------------------------------------------
__global__ __launch_bounds__(256) void emission_kernel(
    const float* __restrict__ feat,
    const float* __restrict__ wmat,
    const float* __restrict__ sinv,
    const float* __restrict__ q2,
    float* __restrict__ emhat,
    float* __restrict__ kmax,
    int D) {
  __shared__ __align__(16) float xsT[DCH][68];
  __shared__ __align__(16) float wsT[DCH][68];
  __shared__ float q2s[CC];
  __shared__ float x2row[64];
  __shared__ float rmx[64][17];
  __shared__ float kapsh[64];
  int tid = threadIdx.x;
  size_t row0 = (size_t)blockIdx.x * 64;
  if (tid < CC) q2s[tid] = q2[tid];
  int lr_ = tid >> 2;
  int lq  = tid & 3;
  int lj  = lq * 8;
  int tx = tid & 15, ty = tid >> 4;
  int r0 = ty * 4, c0 = tx * 4;

  const float* fx = feat + (row0 + (size_t)lr_) * D + lj;
  const float* fw = wmat + (size_t)lr_ * D + lj;
  const float* fs = sinv + lj;

  float4 xa = *(const float4*)(fx);
  float4 xb = *(const float4*)(fx + 4);
  float4 wa = *(const float4*)(fw);
  float4 wb = *(const float4*)(fw + 4);
  float4 sa = *(const float4*)(fs);
  float4 sb = *(const float4*)(fs + 4);

  float acc[4][4] = {{0.f}};
  float x2p = 0.f;

  for (int d0 = 0; d0 < D; d0 += DCH) {
    __syncthreads();
    {
      float xs0 = xa.x * sa.x, xs1 = xa.y * sa.y, xs2 = xa.z * sa.z, xs3 = xa.w * sa.w;
      float xs4 = xb.x * sb.x, xs5 = xb.y * sb.y, xs6 = xb.z * sb.z, xs7 = xb.w * sb.w;
      xsT[lj + 0][lr_] = xs0; xsT[lj + 1][lr_] = xs1;
      xsT[lj + 2][lr_] = xs2; xsT[lj + 3][lr_] = xs3;
      xsT[lj + 4][lr_] = xs4; xsT[lj + 5][lr_] = xs5;
      xsT[lj + 6][lr_] = xs6; xsT[lj + 7][lr_] = xs7;
      wsT[lj + 0][lr_] = wa.x; wsT[lj + 1][lr_] = wa.y;
      wsT[lj + 2][lr_] = wa.z; wsT[lj + 3][lr_] = wa.w;
      wsT[lj + 4][lr_] = wb.x; wsT[lj + 5][lr_] = wb.y;
      wsT[lj + 6][lr_] = wb.z; wsT[lj + 7][lr_] = wb.w;
      x2p = fmaf(xs0, xs0, x2p); x2p = fmaf(xs1, xs1, x2p);
      x2p = fmaf(xs2, xs2, x2p); x2p = fmaf(xs3, xs3, x2p);
      x2p = fmaf(xs4, xs4, x2p); x2p = fmaf(xs5, xs5, x2p);
      x2p = fmaf(xs6, xs6, x2p); x2p = fmaf(xs7, xs7, x2p);
    }
    __syncthreads();
    if (d0 + DCH < D) {
      fx += DCH; fw += DCH; fs += DCH;
      xa = *(const float4*)(fx);
      xb = *(const float4*)(fx + 4);
      wa = *(const float4*)(fw);
      wb = *(const float4*)(fw + 4);
      sa = *(const float4*)(fs);
      sb = *(const float4*)(fs + 4);
    }
    #pragma unroll
    for (int j = 0; j < DCH; ++j) {
      float4 xv = *(const float4*)&xsT[j][r0];
      float4 wv = *(const float4*)&wsT[j][c0];
      acc[0][0] = fmaf(xv.x, wv.x, acc[0][0]);
      acc[0][1] = fmaf(xv.x, wv.y, acc[0][1]);
      acc[0][2] = fmaf(xv.x, wv.z, acc[0][2]);
      acc[0][3] = fmaf(xv.x, wv.w, acc[0][3]);
      acc[1][0] = fmaf(xv.y, wv.x, acc[1][0]);
      acc[1][1] = fmaf(xv.y, wv.y, acc[1][1]);
      acc[1][2] = fmaf(xv.y, wv.z, acc[1][2]);
      acc[1][3] = fmaf(xv.y, wv.w, acc[1][3]);
      acc[2][0] = fmaf(xv.z, wv.x, acc[2][0]);
      acc[2][1] = fmaf(xv.z, wv.y, acc[2][1]);
      acc[2][2] = fmaf(xv.z, wv.z, acc[2][2]);
      acc[2][3] = fmaf(xv.z, wv.w, acc[2][3]);
      acc[3][0] = fmaf(xv.w, wv.x, acc[3][0]);
      acc[3][1] = fmaf(xv.w, wv.y, acc[3][1]);
      acc[3][2] = fmaf(xv.w, wv.z, acc[3][2]);
      acc[3][3] = fmaf(xv.w, wv.w, acc[3][3]);
    }
  }

  x2p += dpp_mov<0xB1, 0>(x2p);
  x2p += dpp_mov<0x4E, 0>(x2p);
  if (lq == 0) x2row[lr_] = x2p;
  __syncthreads();

  float e[4][4];
  #pragma unroll
  for (int i = 0; i < 4; ++i) {
    float h = 0.5f * x2row[r0 + i];
    #pragma unroll
    for (int k2 = 0; k2 < 4; ++k2)
      e[i][k2] = LOG2E * (acc[i][k2] - h) + q2s[c0 + k2];
  }
  #pragma unroll
  for (int i = 0; i < 4; ++i)
    rmx[r0 + i][tx] = fmaxf(fmaxf(e[i][0], e[i][1]), fmaxf(e[i][2], e[i][3]));
  __syncthreads();
  if (tid < 64) {
    float m = rmx[tid][0];
    #pragma unroll
    for (int j = 1; j < 16; ++j) m = fmaxf(m, rmx[tid][j]);
    kapsh[tid] = m;
    kmax[row0 + tid] = m;
  }
  __syncthreads();
  #pragma unroll
  for (int i = 0; i < 4; ++i) {
    float kp = kapsh[r0 + i];
    size_t row = row0 + r0 + i;
    float4 o;
    o.x = EXP2(e[i][0] - kp); o.y = EXP2(e[i][1] - kp);
    o.z = EXP2(e[i][2] - kp); o.w = EXP2(e[i][3] - kp);
    *(float4*)&emhat[row * CC + c0] = o;
  }
}

// ---------------------------------------------------------------------------
// Recursion v8: quad fusion (R10, 243us) with the scalar tail PACKED into
// VOP3P: packed ring A2[j]=(A[2j+1],A[2j+2]); D1..D4 as 34 pk_fma vs 66 fma
// (weight pairs Wq[m]=(W[m],W[m+1]), zero-padded); ring shift-by-4 as 8
// pk_mul; consume reduce as 3 pk_add; prefetch via 4 advancing pointers
// (main loop bounded t<=N-8 so no clamps).
// AE(i) maps scalar ring index -> packed element (tail body1 only).
// ---------------------------------------------------------------------------
#define AE(i) (A2[((i) - 1) >> 1][((i) - 1) & 1])

__global__ __launch_bounds__(64, 1) void recur_kernel(
    const float* __restrict__ emhat,
    const float* __restrict__ kmax,
    const float* __restrict__ P_T,
    const float* __restrict__ init2,
    const float* __restrict__ len2,
    const int* __restrict__ lengths,
    float* __restrict__ out,
    int N) {
  __shared__ __align__(16) float abuf[CC];
  int b = blockIdx.x;
  int c = threadIdx.x;

  v2f P2[CC / 2];
  #pragma unroll
  for (int j = 0; j < CC / 2; ++j) {
    v2f p;
    p.x = P_T[(size_t)(2 * j) * CC + c];
    p.y = P_T[(size_t)(2 * j + 1) * CC + c];
    P2[j] = p;
  }
  float Wl[KK + 1];
  #pragma unroll
  for (int k = 1; k <= KK; ++k) Wl[k] = EXP2(len2[(k - 1) * CC + c]);
  float W1 = Wl[1], w2 = Wl[2], w3 = Wl[3], w4 = Wl[4], w5 = Wl[5];
  // Wq[m] = (W[m], W[m+1]) for m=3..19; Wq[20] = (W[20], 0)
  v2f Wq[21];
  #pragma unroll
  for (int m = 3; m <= 19; ++m) { Wq[m].x = Wl[m]; Wq[m].y = Wl[m + 1]; }
  Wq[20].x = Wl[20]; Wq[20].y = 0.f;

  const float* eh_b = emhat + (size_t)b * N * CC;
  const float* km_b = kmax + (size_t)b * N;
  int len_b = lengths[b];

  float skp = 0.f;
  for (int r = c; r < len_b; r += 64) skp += km_b[r];
  float Skap = wave_sum64(skp);

  float v = EXP2(init2[c]);
  float rho = eh_b[c];  // row 0
  float qa = eh_b[(size_t)(1 <= N - 1 ? 1 : N - 1) * CC + c];
  float qb = eh_b[(size_t)(2 <= N - 1 ? 2 : N - 1) * CC + c];
  float qc = eh_b[(size_t)(3 <= N - 1 ? 3 : N - 1) * CC + c];
  float qd = eh_b[(size_t)(4 <= N - 1 ? 4 : N - 1) * CC + c];
  float EfSum = 0.f;
  v2f A2[10];
  #pragma unroll
  for (int j = 0; j < 10; ++j) { A2[j].x = 0.f; A2[j].y = 0.f; }
  float rest = 0.f;

  // advancing prefetch pointers (rows t+4..t+7 for quad at t; start t=1)
  const float* pa = eh_b + (size_t)5 * CC + c;
  const float* pb = pa + CC;
  const float* pc = pb + CC;
  const float* pd = pc + CC;

  auto bcast = [&](float a, v2f* dst) {
    abuf[c] = a;
    #pragma unroll
    for (int j = 0; j < CC / 4; ++j) {
      v4f t4 = *(v4f*)&abuf[4 * j];
      v2f lo, hi;
      lo.x = t4.x; lo.y = t4.y;
      hi.x = t4.z; hi.y = t4.w;
      dst[2 * j] = lo;
      dst[2 * j + 1] = hi;
    }
  };
  auto consume = [&](const v2f* a2) -> float {
    v2f m0 = {0.f, 0.f}, m1 = {0.f, 0.f}, m2 = {0.f, 0.f}, m3 = {0.f, 0.f};
    #pragma unroll
    for (int j = 0; j < CC / 2; j += 4) {
      m0 = pk_fma(P2[j],     a2[j],     m0);
      m1 = pk_fma(P2[j + 1], a2[j + 1], m1);
      m2 = pk_fma(P2[j + 2], a2[j + 2], m2);
      m3 = pk_fma(P2[j + 3], a2[j + 3], m3);
    }
    v2f s0 = m0 + m1;
    v2f s1 = m2 + m3;
    v2f s = s0 + s1;
    return s.x + s.y;
  };

  auto body4 = [&](int t) {
    v2f a2[CC / 2];
    // ===== sub a (t): renorm step =====
    float A0a = v * rho;
    float aa = fmaf(A0a, W1, rest);
    bcast(aa, a2);
    if (t == len_b) {
      float s_ = wave_sum64(aa);
      if (c == 0) out[b] = LN2 * (Skap + EfSum + LOG2(s_));
    }
    // packed D1..D4 over OLD ring (fills DS shadow)
    v2f d1 = {0.f, 0.f}, d2 = {0.f, 0.f}, d3 = {0.f, 0.f}, d4 = {0.f, 0.f};
    #pragma unroll
    for (int j = 0; j <= 8; ++j) d1 = pk_fma(A2[j], Wq[2 * j + 3], d1);
    #pragma unroll
    for (int j = 0; j <= 8; ++j) d2 = pk_fma(A2[j], Wq[2 * j + 4], d2);
    #pragma unroll
    for (int j = 0; j <= 7; ++j) d3 = pk_fma(A2[j], Wq[2 * j + 5], d3);
    #pragma unroll
    for (int j = 0; j <= 7; ++j) d4 = pk_fma(A2[j], Wq[2 * j + 6], d4);
    float D1 = d1.x + d1.y, D2 = d2.x + d2.y;
    float D3 = d3.x + d3.y, D4 = d4.x + d4.y;
    // renorm (once per quad)
    float vmax = wave_max64(v);
    vmax = fminf(fmaxf(vmax, 1e-20f), 1e20f);
    int eb = (__float_as_int(vmax) >> 23) & 255;
    float scale = __int_as_float((254 - eb) << 23);
    EfSum += (float)(eb - 127);
    float ra = qa * scale;
    qa = *pa; pa += 4 * CC;
    rest = ra * fmaf(A0a, w2, D1);
    v = consume(a2);

    // ===== sub b (t+1) =====
    float A0b = v * ra;
    float ab = fmaf(A0b, W1, rest);
    bcast(ab, a2);
    if (t + 1 == len_b) {
      float s_ = wave_sum64(ab);
      if (c == 0) out[b] = LN2 * (Skap + EfSum + LOG2(s_));
    }
    float rb = qb;
    qb = *pb; pb += 4 * CC;
    rest = rb * fmaf(A0b, w2, ra * fmaf(A0a, w3, D2));
    v = consume(a2);

    // ===== sub c (t+2) =====
    float A0c = v * rb;
    float ac = fmaf(A0c, W1, rest);
    bcast(ac, a2);
    if (t + 2 == len_b) {
      float s_ = wave_sum64(ac);
      if (c == 0) out[b] = LN2 * (Skap + EfSum + LOG2(s_));
    }
    float rc = qc;
    qc = *pc; pc += 4 * CC;
    rest = rc * fmaf(A0c, w2, rb * fmaf(A0b, w3, ra * fmaf(A0a, w4, D3)));
    v = consume(a2);

    // ===== sub d (t+3) =====
    float A0d = v * rc;
    float ad = fmaf(A0d, W1, rest);
    bcast(ad, a2);
    if (t + 3 == len_b) {
      float s_ = wave_sum64(ad);
      if (c == 0) out[b] = LN2 * (Skap + EfSum + LOG2(s_));
    }
    float rd = qd;
    qd = *pd; pd += 4 * CC;
    rest = rd * fmaf(A0d, w2,
                rc * fmaf(A0c, w3,
                rb * fmaf(A0b, w4,
                ra * fmaf(A0a, w5, D4))));
    // packed ring shift by 4 (= 2 pairs)
    float rcd = rc * rd;
    float rbcd = rb * rcd;
    float r4 = ra * rbcd;
    v2f r4v; r4v.x = r4; r4v.y = r4;
    #pragma unroll
    for (int j = 9; j >= 2; --j) A2[j] = A2[j - 2] * r4v;
    A2[1].x = A0b * rbcd; A2[1].y = A0a * r4;
    A2[0].x = A0d * rd;   A2[0].y = A0c * rcd;
    v = consume(a2);

    rho = rd;
  };

  // single-step fallback (tail; per-step renorm; clamped prefetch — exact)
  auto body1 = [&](int t, float& q) {
    v2f a2[CC / 2];
    float A0 = v * rho;
    float a = fmaf(A0, W1, rest);
    bcast(a, a2);
    if (t == len_b) {
      float s_ = wave_sum64(a);
      if (c == 0) out[b] = LN2 * (Skap + EfSum + LOG2(s_));
    }
    v2f d1 = {0.f, 0.f};
    #pragma unroll
    for (int j = 0; j <= 8; ++j) d1 = pk_fma(A2[j], Wq[2 * j + 3], d1);
    float S2 = fmaf(A0, w2, d1.x + d1.y);
    float rh = q;
    int rown = (t + 4 <= N - 1) ? (t + 4) : (N - 1);
    q = eh_b[(size_t)rown * CC + c];
    float vmax = wave_max64(v);
    vmax = fminf(fmaxf(vmax, 1e-20f), 1e20f);
    int eb = (__float_as_int(vmax) >> 23) & 255;
    float scale = __int_as_float((254 - eb) << 23);
    EfSum += (float)(eb - 127);
    float rhon = rh * scale;
    rest = rhon * S2;
    #pragma unroll
    for (int i = 20; i >= 2; --i) AE(i) = AE(i - 1) * rhon;
    AE(1) = A0 * rhon;
    v = consume(a2);
    rho = rhon;
  };

  int t = 1;
  for (; t <= N - 8; t += 4) body4(t);
  for (; t <= N; ++t) {
    int s = t & 3;
    if (s == 1)      body1(t, qa);
    else if (s == 2) body1(t, qb);
    else if (s == 3) body1(t, qc);
    else             body1(t, qd);
  }
}

extern "C" void kernel_launch(void* const* d_in, const int* in_sizes, int n_in,
                              void* d_out, int out_size, void* d_ws, size_t ws_size,
                              hipStream_t stream) {
  const float* feat   = (const float*)d_in[0];
  const int*   lens   = (const int*)d_in[1];
  const float* means  = (const float*)d_in[2];
  const float* cov    = (const float*)d_in[3];
  const float* tl     = (const float*)d_in[4];
  const float* il     = (const float*)d_in[5];
  const float* plr    = (const float*)d_in[6];
  int B = in_sizes[1];
  int D = in_sizes[2] / CC;
  int N = in_sizes[0] / (B * D);

  float* ws = (float*)d_ws;
  size_t off = 0;
  float* wmat   = ws + off; off += (size_t)CC * D;
  float* invvar = ws + off; off += D;
  float* sinv   = ws + off; off += D;
  float* q2     = ws + off; off += CC;
  float* P_T    = ws + off; off += CC * CC;
  float* init2  = ws + off; off += CC;
  float* len2   = ws + off; off += KK * CC;
  float* emhat  = ws + off; off += (size_t)B * N * CC;
  float* kmax   = ws + off; off += (size_t)B * N;

  hipLaunchKernelGGL(setup_kernel, dim3(1), dim3(256), 0, stream,
                     means, cov, tl, il, plr, wmat, invvar, sinv, q2, P_T, init2, len2, D);
  hipLaunchKernelGGL(emission_kernel, dim3((B * N) / 64), dim3(256), 0, stream,
                     feat, wmat, sinv, q2, emhat, kmax, D);
  hipLaunchKernelGGL(recur_kernel, dim3(B), dim3(64), 0, stream,
                     emhat, kmax, P_T, init2, len2, lens, (float*)d_out, N);
}